// Round 10
// baseline (252.596 us; speedup 1.0000x reference)
//
#include <hip/hip_runtime.h>
#include <hip/hip_bf16.h>
#include <math.h>

// Problem constants (from reference)
#define DM   1024        // d_model
#define DI   2048        // d_inner
#define DS   16          // d_state
#define DTR  64          // dt_rank
#define NB   2           // batch
#define LL   1024        // seq len
#define MR   (NB*LL)     // 2048 rows (b*l flattened)
#define XDBL 96          // dt_rank + 2*d_state
#define NC   32          // scan chunks
#define CL   32          // chunk length (NC*CL == LL)

typedef _Float16 half8  __attribute__((ext_vector_type(8)));
typedef _Float16 half4v __attribute__((ext_vector_type(4)));
typedef float    floatx4 __attribute__((ext_vector_type(4)));

__device__ __forceinline__ void gload_lds16(const void* g, void* l) {
  __builtin_amdgcn_global_load_lds(
      (const __attribute__((address_space(1))) void*)g,
      (__attribute__((address_space(3))) void*)l, 16, 0, 0);
}

// ---------------------------------------------------------------------------
// Front kernel: LN (blocks 0..2047) + weight f2h.
// ---------------------------------------------------------------------------
__global__ __launch_bounds__(256) void front_kernel(
    const float* __restrict__ x, const float* __restrict__ ln_w,
    const float* __restrict__ ln_b,
    const float* __restrict__ w_in, const float* __restrict__ w_out,
    const float* __restrict__ w_xp, const float* __restrict__ w_dt,
    _Float16* __restrict__ h_h,
    _Float16* __restrict__ w_in_h, _Float16* __restrict__ w_out_h,
    _Float16* __restrict__ w_xp_h, _Float16* __restrict__ w_dt_h) {
  const int blk = blockIdx.x;
  if (blk < MR) {
    __shared__ float sA[4], sB[4];
    const float* xr = x + (size_t)blk * DM;
    float s = 0.f, ss = 0.f;
    for (int i = threadIdx.x; i < DM; i += 256) {
      float v = xr[i];
      s += v; ss += v * v;
    }
    for (int o = 32; o > 0; o >>= 1) {
      s  += __shfl_down(s, o, 64);
      ss += __shfl_down(ss, o, 64);
    }
    const int wid = threadIdx.x >> 6, lid = threadIdx.x & 63;
    if (lid == 0) { sA[wid] = s; sB[wid] = ss; }
    __syncthreads();
    if (threadIdx.x == 0) {
      float S = sA[0] + sA[1] + sA[2] + sA[3];
      float SS = sB[0] + sB[1] + sB[2] + sB[3];
      float mu = S / DM;
      sA[0] = mu;
      sB[0] = rsqrtf(SS / DM - mu * mu + 1e-5f);
    }
    __syncthreads();
    const float mu = sA[0], rs = sB[0];
    for (int i = threadIdx.x; i < DM; i += 256)
      h_h[(size_t)blk * DM + i] = (_Float16)((xr[i] - mu) * rs * ln_w[i] + ln_b[i]);
    return;
  }
  int i = (blk - MR) * 256 + threadIdx.x;
  const int N0 = 1048576, N1 = 524288, N2 = 49152, N3 = 32768;
  const float* s; _Float16* d; int off;
  if (i < N0)            { s = w_in;  d = w_in_h;  off = i; }
  else if (i < N0+N1)    { s = w_out; d = w_out_h; off = i - N0; }
  else if (i < N0+N1+N2) { s = w_xp;  d = w_xp_h;  off = i - N0 - N1; }
  else if (i < N0+N1+N2+N3) { s = w_dt; d = w_dt_h; off = i - N0 - N1 - N2; }
  else return;
  float4 v = ((const float4*)s)[off];
  half4v h = {(_Float16)v.x, (_Float16)v.y, (_Float16)v.z, (_Float16)v.w};
  ((half4v*)d)[off] = h;
}

// ---------------------------------------------------------------------------
// MFMA f16 GEMM, double-buffered LDS pipeline + XOR bank swizzle.
// C[m,n] = sum_k A[m,k]*W[n,k], fp32 accumulate. Tile 128 x TN, BK=32,
// 4 waves each 64 x TN/2 (TN=32: 64x16).
// LDS layout: logical 16B chunk c of row r stored at physical chunk
// c ^ ((r>>1)&3). Fixes the 8-way ds_read_b128 bank conflict of the plain
// row-major 64B-stride layout (r9: 5.2M SQ_LDS_BANK_CONFLICT on in_proj,
// LDS-bound at 24 TB/s = 69/2.9). Swizzle term is lane-constant on both
// write (global fetch chunk select) and read ((r>>1)&3 == (fr>>1)&3).
// EPI 0: dual f16 store (n<DI -> Cv, else C2v; compact DI-wide rows)
// EPI 1: f32 store softplus(acc + extra[n])  [fast-math __logf/__expf]
// EPI 2: f32 store acc + extra[m*ldc+n] (fused residual)
// EPI 4: f32 partial store at Cv + blockIdx.z*M*ldc (split-K, no atomics)
// ---------------------------------------------------------------------------
template <int EPI, int TN>
__global__ __launch_bounds__(256) void gemm_mfma(
    const _Float16* __restrict__ A,   // [M][K]
    const _Float16* __restrict__ W,   // [N][K]
    void* __restrict__ Cv, void* __restrict__ C2v,
    const float* __restrict__ extra, int ldc,
    int M, int N, int K, int kchunk) {
  constexpr int NT = (TN + 31) / 32;   // 16-col tiles per wave (1,2,3)
  constexpr int WSLOT = TN / 16;       // W staging slots (512 halves each)
  __shared__ alignas(16) _Float16 As[2][128 * 32];
  __shared__ alignas(16) _Float16 Ws[2][TN * 32];
  const int t = threadIdx.x;
  const int wave = t >> 6, lane = t & 63;
  const int m0 = blockIdx.y * 128, n0 = blockIdx.x * TN;
  const int k_beg = blockIdx.z * kchunk;
  const int nk = kchunk >> 5;
  const int wm = (wave >> 1) * 64, wn = (wave & 1) * (TN / 2);
  floatx4 acc[4][NT];
#pragma unroll
  for (int i = 0; i < 4; i++)
#pragma unroll
    for (int j = 0; j < NT; j++) acc[i][j] = {0.f, 0.f, 0.f, 0.f};

  const int fr = lane & 15;     // row within 16-tile
  const int kc8 = lane >> 4;    // logical 8-half k-chunk this lane consumes
  const int kp = (kc8 ^ ((fr >> 1) & 3)) * 8;   // swizzled physical chunk (halves)

  auto stage = [&](int buf, int k0) {
    for (int sl = wave; sl < 8; sl += 4) {
      const int idx = sl * 64 + lane;
      const int row = idx >> 2;
      const int kc = (idx & 3) ^ ((row >> 1) & 3);   // XOR-swizzled fetch
      gload_lds16(A + (size_t)(m0 + row) * K + k0 + kc * 8, &As[buf][sl * 512]);
    }
    for (int sl = wave; sl < WSLOT; sl += 4) {
      const int idx = sl * 64 + lane;
      const int row = idx >> 2;
      const int kc = (idx & 3) ^ ((row >> 1) & 3);
      const int wrow = (n0 + row < N) ? row : 0;   // safety clamp
      gload_lds16(W + (size_t)(n0 + wrow) * K + k0 + kc * 8, &Ws[buf][sl * 512]);
    }
  };

  stage(0, k_beg);
  int cur = 0;
  for (int ki = 0; ki < nk; ki++) {
    __syncthreads();                       // stage(cur) complete; prior reads done
    if (ki + 1 < nk) stage(cur ^ 1, k_beg + ((ki + 1) << 5));   // async prefetch
    half8 af[4], wf[NT];
#pragma unroll
    for (int i = 0; i < 4; i++)
      af[i] = *(const half8*)&As[cur][(wm + i * 16 + fr) * 32 + kp];
#pragma unroll
    for (int j = 0; j < NT; j++)
      wf[j] = *(const half8*)&Ws[cur][(wn + j * 16 + fr) * 32 + kp];
#pragma unroll
    for (int i = 0; i < 4; i++)
#pragma unroll
      for (int j = 0; j < NT; j++)
        acc[i][j] = __builtin_amdgcn_mfma_f32_16x16x32_f16(af[i], wf[j], acc[i][j], 0, 0, 0);
    cur ^= 1;
  }

  // epilogue: C/D layout col = lane&15, row = (lane>>4)*4 + reg
  const int col = lane & 15, rowq = lane >> 4;
#pragma unroll
  for (int i = 0; i < 4; i++) {
#pragma unroll
    for (int j = 0; j < NT; j++) {
      const int n = n0 + wn + j * 16 + col;
      if (n < N) {
#pragma unroll
        for (int r = 0; r < 4; r++) {
          const int m = m0 + wm + i * 16 + rowq * 4 + r;
          float v = acc[i][j][r];
          if (EPI == 0) {
            if (n < DI) ((_Float16*)Cv )[(size_t)m * DI + n]      = (_Float16)v;
            else        ((_Float16*)C2v)[(size_t)m * DI + n - DI] = (_Float16)v;
          } else if (EPI == 1) {
            v += extra[n];
            v = (v > 20.f) ? v : __logf(1.f + __expf(v));   // fast softplus
            ((float*)Cv)[(size_t)m * ldc + n] = v;
          } else if (EPI == 2) {
            ((float*)Cv)[(size_t)m * ldc + n] = v + extra[(size_t)m * ldc + n];
          } else if (EPI == 4) {
            ((float*)Cv)[((size_t)blockIdx.z * M + m) * ldc + n] = v;
          }
        }
      }
    }
  }
}

// ---------------------------------------------------------------------------
// x_proj partial reduce: x_dbl = sum_z part[z], also emit dtr f16 (cols<64).
// ---------------------------------------------------------------------------
__global__ __launch_bounds__(256) void xproj_reduce(
    const float* __restrict__ part,      // [16][MR][XDBL]
    float* __restrict__ x_dbl, _Float16* __restrict__ dtr) {
  const int idx = blockIdx.x * 256 + threadIdx.x;   // MR*XDBL = 196608
  const int m = idx / XDBL, c = idx - m * XDBL;
  float s = 0.f;
#pragma unroll
  for (int z = 0; z < 16; z++) s += part[(size_t)z * (MR * XDBL) + idx];
  x_dbl[idx] = s;
  if (c < DTR) dtr[m * DTR + c] = (_Float16)s;
}

// ---------------------------------------------------------------------------
// out_proj partial reduce + residual: out = x + p0 + p1.
// ---------------------------------------------------------------------------
__global__ __launch_bounds__(256) void out_reduce(
    const float* __restrict__ x, const float* __restrict__ part,  // [2][MR][DM]
    float* __restrict__ out) {
  const int i = blockIdx.x * 256 + threadIdx.x;   // MR*DM/4 = 524288
  float4 a  = ((const float4*)x)[i];
  float4 p0 = ((const float4*)part)[i];
  float4 p1 = ((const float4*)(part + (size_t)MR * DM))[i];
  ((float4*)out)[i] = make_float4(a.x + p0.x + p1.x, a.y + p0.y + p1.y,
                                  a.z + p0.z + p1.z, a.w + p0.w + p1.w);
}

// ---------------------------------------------------------------------------
// Depthwise causal conv1d (width 4) + bias + SiLU, 8 channels per thread.
// ---------------------------------------------------------------------------
__global__ __launch_bounds__(256) void conv_silu_kernel(
    const _Float16* __restrict__ xin, const float* __restrict__ cw,
    const float* __restrict__ cb, _Float16* __restrict__ xc) {
  const int idx = blockIdx.x * 256 + threadIdx.x;   // 0 .. MR*DI/8-1
  const int d8 = idx & (DI / 8 - 1);
  const int ml = idx >> 8;
  const int l  = ml & (LL - 1);
  const int d0 = d8 * 8;
  half8 xr[4];
  const half8 zero = {0, 0, 0, 0, 0, 0, 0, 0};
#pragma unroll
  for (int k = 0; k < 4; k++) {
    const int lp = l - 3 + k;
    xr[k] = (lp >= 0) ? *(const half8*)&xin[(size_t)(ml - 3 + k) * DI + d0] : zero;
  }
  half8 o;
#pragma unroll
  for (int j = 0; j < 8; j++) {
    float acc = cb[d0 + j];
#pragma unroll
    for (int k = 0; k < 4; k++)
      acc += (float)xr[k][j] * cw[(d0 + j) * 4 + k];
    o[j] = (_Float16)(acc / (1.f + __expf(-acc)));
  }
  *(half8*)&xc[(size_t)ml * DI + d0] = o;
}

// ---------------------------------------------------------------------------
// Load per-channel A row; detect S4D-real init a[s] == -(s+1) (uniform).
// ---------------------------------------------------------------------------
__device__ __forceinline__ bool load_a(const float* __restrict__ A_log, int d,
                                       float* a) {
  const float4* Ap = (const float4*)(A_log + (size_t)d * DS);
  bool fast = true;
#pragma unroll
  for (int i = 0; i < 4; i++) {
    float4 v = Ap[i];
    a[4 * i + 0] = -__expf(v.x); a[4 * i + 1] = -__expf(v.y);
    a[4 * i + 2] = -__expf(v.z); a[4 * i + 3] = -__expf(v.w);
  }
#pragma unroll
  for (int s = 0; s < DS; s++)
    fast = fast && (fabsf(a[s] + (float)(s + 1)) < 1e-4f);
  return fast;
}

// ---------------------------------------------------------------------------
// Chunked selective scan, phase 1: per-(b,chunk) local scan with h=0 init.
// Fast path: exp(dt*a[s]) = r^(s+1), r = exp(-dt)  (1 exp + 15 mul vs 16 exp).
// ---------------------------------------------------------------------------
__global__ __launch_bounds__(256) void scan_phase1(
    const _Float16* __restrict__ xc,  // x_conv (MR x DI) f16
    const float* __restrict__ xdbl,   // (MR x 96)
    const float* __restrict__ dtm,    // dt after softplus (MR x DI) f32
    const float* __restrict__ A_log,
    float* __restrict__ HE,           // (NB*NC*DS) x DI
    float* __restrict__ SA) {         // (NB*NC) x DI
  __shared__ float Bs[CL][DS];
  const int bi = blockIdx.x;
  const int dblk = bi & 7;
  const int c = (bi >> 3) & (NC - 1);
  const int b = bi >> 8;
  const int t = threadIdx.x;
  const int d = dblk * 256 + t;
  const int mlbase = b * LL + c * CL;

  for (int i = t; i < CL * DS; i += 256) {
    int tt = i >> 4, s = i & 15;
    Bs[tt][s] = xdbl[(size_t)(mlbase + tt) * XDBL + DTR + s];
  }

  float a[DS];
  const bool fast = load_a(A_log, d, a);
  float h[DS];
#pragma unroll
  for (int s = 0; s < DS; s++) h[s] = 0.f;
  float S = 0.f;
  __syncthreads();

  if (fast) {
    for (int tt = 0; tt < CL; tt++) {
      const size_t ml = mlbase + tt;
      const float dtv = dtm[ml * DI + d];
      const float u   = (float)xc[ml * DI + d];
      const float du  = dtv * u;
      S += dtv;
      const float r = __expf(-dtv);
      float P = 1.f;
#pragma unroll
      for (int s = 0; s < DS; s++) {
        P *= r;
        h[s] = P * h[s] + du * Bs[tt][s];
      }
    }
  } else {
    for (int tt = 0; tt < CL; tt++) {
      const size_t ml = mlbase + tt;
      const float dtv = dtm[ml * DI + d];
      const float u   = (float)xc[ml * DI + d];
      const float du  = dtv * u;
      S += dtv;
#pragma unroll
      for (int s = 0; s < DS; s++)
        h[s] = __expf(dtv * a[s]) * h[s] + du * Bs[tt][s];
    }
  }
  const size_t base = ((size_t)(b * NC + c) * DS) * DI + d;
#pragma unroll
  for (int s = 0; s < DS; s++) HE[base + (size_t)s * DI] = h[s];
  SA[(size_t)(b * NC + c) * DI + d] = S;
}

// ---------------------------------------------------------------------------
// Phase 2: sequential combine over chunk aggregates; HE becomes carry-in.
// ---------------------------------------------------------------------------
__global__ __launch_bounds__(256) void scan_phase2(
    const float* __restrict__ A_log,
    const float* __restrict__ SA,
    float* __restrict__ HE) {
  const int idx = blockIdx.x * 256 + threadIdx.x;  // NB*DS*DI
  const int d = idx & (DI - 1);
  const int s = (idx >> 11) & (DS - 1);
  const int b = idx >> 15;
  const float a = -__expf(A_log[(size_t)d * DS + s]);
  float Hc = 0.f;
  for (int c = 0; c < NC; c++) {
    const size_t o = ((size_t)(b * NC + c) * DS + s) * DI + d;
    const float he = HE[o];
    const float P = __expf(a * SA[(size_t)(b * NC + c) * DI + d]);
    HE[o] = Hc;
    Hc = P * Hc + he;
  }
}

// ---------------------------------------------------------------------------
// Phase 3: re-run chunks with carry-in; fuse y = (sum_s h*C + u*D)*silu(z).
// ---------------------------------------------------------------------------
__global__ __launch_bounds__(256) void scan_phase3(
    const _Float16* __restrict__ xc,
    const float* __restrict__ xdbl,
    const float* __restrict__ dtm,      // f32
    const _Float16* __restrict__ zbuf,  // z (MR x DI) f16
    const float* __restrict__ A_log,
    const float* __restrict__ Dvec,
    const float* __restrict__ HE,
    _Float16* __restrict__ y) {         // (MR x DI) f16
  __shared__ float Bs[CL][DS];
  __shared__ float Cs[CL][DS];
  const int bi = blockIdx.x;
  const int dblk = bi & 7;
  const int c = (bi >> 3) & (NC - 1);
  const int b = bi >> 8;
  const int t = threadIdx.x;
  const int d = dblk * 256 + t;
  const int mlbase = b * LL + c * CL;

  for (int i = t; i < CL * DS; i += 256) {
    int tt = i >> 4, s = i & 15;
    const size_t ro = (size_t)(mlbase + tt) * XDBL + DTR + s;
    Bs[tt][s] = xdbl[ro];
    Cs[tt][s] = xdbl[ro + DS];
  }

  float a[DS];
  const bool fast = load_a(A_log, d, a);
  float h[DS];
  const size_t base = ((size_t)(b * NC + c) * DS) * DI + d;
#pragma unroll
  for (int s = 0; s < DS; s++) h[s] = HE[base + (size_t)s * DI];
  const float Dv = Dvec[d];
  __syncthreads();

  if (fast) {
    for (int tt = 0; tt < CL; tt++) {
      const size_t ml = mlbase + tt;
      const float dtv = dtm[ml * DI + d];
      const float u   = (float)xc[ml * DI + d];
      const float du  = dtv * u;
      const float r = __expf(-dtv);
      float P = 1.f, p = 0.f;
#pragma unroll
      for (int s = 0; s < DS; s++) {
        P *= r;
        h[s] = P * h[s] + du * Bs[tt][s];
        p += h[s] * Cs[tt][s];
      }
      const float zv = (float)zbuf[ml * DI + d];
      const float sil = zv / (1.f + __expf(-zv));
      y[ml * DI + d] = (_Float16)((p + u * Dv) * sil);
    }
  } else {
    for (int tt = 0; tt < CL; tt++) {
      const size_t ml = mlbase + tt;
      const float dtv = dtm[ml * DI + d];
      const float u   = (float)xc[ml * DI + d];
      const float du  = dtv * u;
      float p = 0.f;
#pragma unroll
      for (int s = 0; s < DS; s++) {
        h[s] = __expf(dtv * a[s]) * h[s] + du * Bs[tt][s];
        p += h[s] * Cs[tt][s];
      }
      const float zv = (float)zbuf[ml * DI + d];
      const float sil = zv / (1.f + __expf(-zv));
      y[ml * DI + d] = (_Float16)((p + u * Dv) * sil);
    }
  }
}

// ---------------------------------------------------------------------------
// Launch
// ---------------------------------------------------------------------------
extern "C" void kernel_launch(void* const* d_in, const int* in_sizes, int n_in,
                              void* d_out, int out_size, void* d_ws, size_t ws_size,
                              hipStream_t stream) {
  const float* x         = (const float*)d_in[0];
  const float* ln_w      = (const float*)d_in[1];
  const float* ln_b      = (const float*)d_in[2];
  const float* in_proj_w = (const float*)d_in[3];   // (4096, 1024)
  const float* conv_w    = (const float*)d_in[4];   // (2048, 1, 4)
  const float* conv_b    = (const float*)d_in[5];
  const float* x_proj_w  = (const float*)d_in[6];   // (96, 2048)
  const float* dt_proj_w = (const float*)d_in[7];   // (2048, 64)
  const float* dt_proj_b = (const float*)d_in[8];
  const float* A_log     = (const float*)d_in[9];   // (2048, 16)
  const float* Dvec      = (const float*)d_in[10];
  const float* out_proj_w= (const float*)d_in[11];  // (1024, 2048)
  float* out = (float*)d_out;

  // workspace layout (bytes; total ~82 MB)
  char* ws = (char*)d_ws;
  _Float16* h_h     = (_Float16*)ws;                 //  4 MB (MR*DM) — dead after in_proj
  _Float16* xin_h   = (_Float16*)(ws + 4194304);     //  8 MB — dead after conv
  _Float16* y_h     = xin_h;                         //  aliases xin
  _Float16* z_h     = (_Float16*)(ws + 12582912);    //  8 MB
  _Float16* xc_h    = (_Float16*)(ws + 20971520);    //  8 MB
  float*    dtb     = (float*)   (ws + 29360128);    // 16 MB (MR*DI f32) — dead after p3
  float*    out_part= dtb;                           // 16 MB (2 x MR x DM f32), aliases dtb
  float*    x_dbl   = (float*)   (ws + 46137344);    //  0.75 MB
  float*    SA      = (float*)   (ws + 46923776);    //  0.5 MB
  _Float16* dtr_h   = (_Float16*)(ws + 47448064);    //  0.25 MB
  float*    HE      = (float*)   (ws + 47710208);    //  8 MB
  _Float16* w_in_h  = (_Float16*)(ws + 56098816);    //  8 MB
  _Float16* w_out_h = (_Float16*)(ws + 64487424);    //  4 MB
  _Float16* w_xp_h  = (_Float16*)(ws + 68681728);    //  0.375 MB
  _Float16* w_dt_h  = (_Float16*)(ws + 69074944);    //  0.25 MB
  float*    xp_part = (float*)   (ws + 69337088);    // 12.6 MB (16 x MR x 96 f32)

  // 0+1. fused: layernorm + weight f2h
  front_kernel<<<MR + 6464, 256, 0, stream>>>(
      x, ln_w, ln_b, in_proj_w, out_proj_w, x_proj_w, dt_proj_w,
      h_h, w_in_h, w_out_h, w_xp_h, w_dt_h);

  // 2. in_proj: N=4096, tile 128x32 -> 2048 blocks (8/CU), dual f16 store
  gemm_mfma<0, 32><<<dim3(2 * DI / 32, MR / 128, 1), 256, 0, stream>>>(
      h_h, w_in_h, xin_h, z_h, nullptr, 0, MR, 2 * DI, DM, DM);

  // 3. conv + silu -> xc_h (f16), 8 channels/thread
  conv_silu_kernel<<<(MR * DI / 8) / 256, 256, 0, stream>>>(xin_h, conv_w, conv_b, xc_h);

  // 4. x_proj: tile 128x96, split-K 16 -> streaming partials (no atomics)
  gemm_mfma<4, 96><<<dim3(1, MR / 128, 16), 256, 0, stream>>>(
      xc_h, w_xp_h, xp_part, nullptr, nullptr, XDBL, MR, XDBL, DI, DI / 16);
  xproj_reduce<<<(MR * XDBL) / 256, 256, 0, stream>>>(xp_part, x_dbl, dtr_h);

  // 5. dt: MFMA + fast softplus -> f32 dtb (tile 128x64), K=64
  gemm_mfma<1, 64><<<dim3(DI / 64, MR / 128, 1), 256, 0, stream>>>(
      dtr_h, w_dt_h, dtb, nullptr, dt_proj_b, DI, MR, DI, DTR, DTR);

  // 6. chunked selective scan
  scan_phase1<<<NB * NC * (DI / 256), 256, 0, stream>>>(
      xc_h, x_dbl, dtb, A_log, HE, SA);
  scan_phase2<<<(NB * DS * DI) / 256, 256, 0, stream>>>(A_log, SA, HE);
  scan_phase3<<<NB * NC * (DI / 256), 256, 0, stream>>>(
      xc_h, x_dbl, dtb, z_h, A_log, Dvec, HE, y_h);

  // 7. out_proj: tile 128x32, split-K 2 -> 1024 blocks (4/CU), streaming
  //    partials into dead dtb, then out = x + p0 + p1
  gemm_mfma<4, 32><<<dim3(DM / 32, MR / 128, 2), 256, 0, stream>>>(
      y_h, w_out_h, out_part, nullptr, nullptr, DM, MR, DM, DI, DI / 2);
  out_reduce<<<(MR * DM / 4) / 256, 256, 0, stream>>>(x, out_part, out);
}

// Round 11
// 230.804 us; speedup vs baseline: 1.0944x; 1.0944x over previous
//
#include <hip/hip_runtime.h>
#include <hip/hip_bf16.h>
#include <math.h>

// Problem constants (from reference)
#define DM   1024        // d_model
#define DI   2048        // d_inner
#define DS   16          // d_state
#define DTR  64          // dt_rank
#define NB   2           // batch
#define LL   1024        // seq len
#define MR   (NB*LL)     // 2048 rows (b*l flattened)
#define XDBL 96          // dt_rank + 2*d_state
#define NC   32          // scan chunks
#define CL   32          // chunk length (NC*CL == LL)

typedef _Float16 half8  __attribute__((ext_vector_type(8)));
typedef _Float16 half4v __attribute__((ext_vector_type(4)));
typedef float    floatx4 __attribute__((ext_vector_type(4)));

__device__ __forceinline__ void gload_lds16(const void* g, void* l) {
  __builtin_amdgcn_global_load_lds(
      (const __attribute__((address_space(1))) void*)g,
      (__attribute__((address_space(3))) void*)l, 16, 0, 0);
}

// ---------------------------------------------------------------------------
// Front kernel: LN (blocks 0..2047) + weight f2h.
// ---------------------------------------------------------------------------
__global__ __launch_bounds__(256) void front_kernel(
    const float* __restrict__ x, const float* __restrict__ ln_w,
    const float* __restrict__ ln_b,
    const float* __restrict__ w_in, const float* __restrict__ w_out,
    const float* __restrict__ w_xp, const float* __restrict__ w_dt,
    _Float16* __restrict__ h_h,
    _Float16* __restrict__ w_in_h, _Float16* __restrict__ w_out_h,
    _Float16* __restrict__ w_xp_h, _Float16* __restrict__ w_dt_h) {
  const int blk = blockIdx.x;
  if (blk < MR) {
    __shared__ float sA[4], sB[4];
    const float* xr = x + (size_t)blk * DM;
    float s = 0.f, ss = 0.f;
    for (int i = threadIdx.x; i < DM; i += 256) {
      float v = xr[i];
      s += v; ss += v * v;
    }
    for (int o = 32; o > 0; o >>= 1) {
      s  += __shfl_down(s, o, 64);
      ss += __shfl_down(ss, o, 64);
    }
    const int wid = threadIdx.x >> 6, lid = threadIdx.x & 63;
    if (lid == 0) { sA[wid] = s; sB[wid] = ss; }
    __syncthreads();
    if (threadIdx.x == 0) {
      float S = sA[0] + sA[1] + sA[2] + sA[3];
      float SS = sB[0] + sB[1] + sB[2] + sB[3];
      float mu = S / DM;
      sA[0] = mu;
      sB[0] = rsqrtf(SS / DM - mu * mu + 1e-5f);
    }
    __syncthreads();
    const float mu = sA[0], rs = sB[0];
    for (int i = threadIdx.x; i < DM; i += 256)
      h_h[(size_t)blk * DM + i] = (_Float16)((xr[i] - mu) * rs * ln_w[i] + ln_b[i]);
    return;
  }
  int i = (blk - MR) * 256 + threadIdx.x;
  const int N0 = 1048576, N1 = 524288, N2 = 49152, N3 = 32768;
  const float* s; _Float16* d; int off;
  if (i < N0)            { s = w_in;  d = w_in_h;  off = i; }
  else if (i < N0+N1)    { s = w_out; d = w_out_h; off = i - N0; }
  else if (i < N0+N1+N2) { s = w_xp;  d = w_xp_h;  off = i - N0 - N1; }
  else if (i < N0+N1+N2+N3) { s = w_dt; d = w_dt_h; off = i - N0 - N1 - N2; }
  else return;
  float4 v = ((const float4*)s)[off];
  half4v h = {(_Float16)v.x, (_Float16)v.y, (_Float16)v.z, (_Float16)v.w};
  ((half4v*)d)[off] = h;
}

// ---------------------------------------------------------------------------
// MFMA f16 GEMM, double-buffered LDS pipeline + XOR bank swizzle.
// C[m,n] = sum_k A[m,k]*W[n,k], fp32 accumulate. Tile 128 x TN, BK=32,
// 4 waves each 64 x TN/2.
// r10 lesson: bank conflicts were NOT the limiter (5.2M->0, dur unchanged);
// the limiter is latency per K-step slot (~500 cyc). Fewer/fatter slots win:
// TN=128 gives 8 B LDS-read per MFMA (vs 20 B at TN=32) and 64 slots/CU
// (vs 256).
// EPI 0: dual f16 store (n<DI -> Cv, else C2v; compact DI-wide rows)
// EPI 1: f32 store softplus(acc + extra[n])  [fast-math __logf/__expf]
// EPI 2: f32 store acc + extra[m*ldc+n] (fused residual)
// EPI 4: f32 partial store at Cv + blockIdx.z*M*ldc (split-K, no atomics)
// ---------------------------------------------------------------------------
template <int EPI, int TN>
__global__ __launch_bounds__(256) void gemm_mfma(
    const _Float16* __restrict__ A,   // [M][K]
    const _Float16* __restrict__ W,   // [N][K]
    void* __restrict__ Cv, void* __restrict__ C2v,
    const float* __restrict__ extra, int ldc,
    int M, int N, int K, int kchunk) {
  constexpr int NT = (TN + 31) / 32;   // 16-col tiles per wave (1,2,3,4)
  constexpr int WSLOT = TN / 16;       // W staging slots (512 halves each)
  __shared__ alignas(16) _Float16 As[2][128 * 32];
  __shared__ alignas(16) _Float16 Ws[2][TN * 32];
  const int t = threadIdx.x;
  const int wave = t >> 6, lane = t & 63;
  const int m0 = blockIdx.y * 128, n0 = blockIdx.x * TN;
  const int k_beg = blockIdx.z * kchunk;
  const int nk = kchunk >> 5;
  const int wm = (wave >> 1) * 64, wn = (wave & 1) * (TN / 2);
  floatx4 acc[4][NT];
#pragma unroll
  for (int i = 0; i < 4; i++)
#pragma unroll
    for (int j = 0; j < NT; j++) acc[i][j] = {0.f, 0.f, 0.f, 0.f};

  const int fr = lane & 15;     // row within 16-tile
  const int kc8 = lane >> 4;    // logical 8-half k-chunk this lane consumes
  const int kp = (kc8 ^ ((fr >> 1) & 3)) * 8;   // swizzled physical chunk (halves)

  auto stage = [&](int buf, int k0) {
    for (int sl = wave; sl < 8; sl += 4) {
      const int idx = sl * 64 + lane;
      const int row = idx >> 2;
      const int kc = (idx & 3) ^ ((row >> 1) & 3);   // XOR-swizzled fetch
      gload_lds16(A + (size_t)(m0 + row) * K + k0 + kc * 8, &As[buf][sl * 512]);
    }
    for (int sl = wave; sl < WSLOT; sl += 4) {
      const int idx = sl * 64 + lane;
      const int row = idx >> 2;
      const int kc = (idx & 3) ^ ((row >> 1) & 3);
      const int wrow = (n0 + row < N) ? row : 0;   // safety clamp
      gload_lds16(W + (size_t)(n0 + wrow) * K + k0 + kc * 8, &Ws[buf][sl * 512]);
    }
  };

  stage(0, k_beg);
  int cur = 0;
  for (int ki = 0; ki < nk; ki++) {
    __syncthreads();                       // stage(cur) complete; prior reads done
    if (ki + 1 < nk) stage(cur ^ 1, k_beg + ((ki + 1) << 5));   // async prefetch
    half8 af[4], wf[NT];
#pragma unroll
    for (int i = 0; i < 4; i++)
      af[i] = *(const half8*)&As[cur][(wm + i * 16 + fr) * 32 + kp];
#pragma unroll
    for (int j = 0; j < NT; j++)
      wf[j] = *(const half8*)&Ws[cur][(wn + j * 16 + fr) * 32 + kp];
#pragma unroll
    for (int i = 0; i < 4; i++)
#pragma unroll
      for (int j = 0; j < NT; j++)
        acc[i][j] = __builtin_amdgcn_mfma_f32_16x16x32_f16(af[i], wf[j], acc[i][j], 0, 0, 0);
    cur ^= 1;
  }

  // epilogue: C/D layout col = lane&15, row = (lane>>4)*4 + reg
  const int col = lane & 15, rowq = lane >> 4;
#pragma unroll
  for (int i = 0; i < 4; i++) {
#pragma unroll
    for (int j = 0; j < NT; j++) {
      const int n = n0 + wn + j * 16 + col;
      if (n < N) {
#pragma unroll
        for (int r = 0; r < 4; r++) {
          const int m = m0 + wm + i * 16 + rowq * 4 + r;
          float v = acc[i][j][r];
          if (EPI == 0) {
            if (n < DI) ((_Float16*)Cv )[(size_t)m * DI + n]      = (_Float16)v;
            else        ((_Float16*)C2v)[(size_t)m * DI + n - DI] = (_Float16)v;
          } else if (EPI == 1) {
            v += extra[n];
            v = (v > 20.f) ? v : __logf(1.f + __expf(v));   // fast softplus
            ((float*)Cv)[(size_t)m * ldc + n] = v;
          } else if (EPI == 2) {
            ((float*)Cv)[(size_t)m * ldc + n] = v + extra[(size_t)m * ldc + n];
          } else if (EPI == 4) {
            ((float*)Cv)[((size_t)blockIdx.z * M + m) * ldc + n] = v;
          }
        }
      }
    }
  }
}

// ---------------------------------------------------------------------------
// x_proj partial reduce: x_dbl = sum_z part[z], also emit dtr f16 (cols<64).
// ---------------------------------------------------------------------------
__global__ __launch_bounds__(256) void xproj_reduce(
    const float* __restrict__ part,      // [16][MR][XDBL]
    float* __restrict__ x_dbl, _Float16* __restrict__ dtr) {
  const int idx = blockIdx.x * 256 + threadIdx.x;   // MR*XDBL = 196608
  const int m = idx / XDBL, c = idx - m * XDBL;
  float s = 0.f;
#pragma unroll
  for (int z = 0; z < 16; z++) s += part[(size_t)z * (MR * XDBL) + idx];
  x_dbl[idx] = s;
  if (c < DTR) dtr[m * DTR + c] = (_Float16)s;
}

// ---------------------------------------------------------------------------
// out_proj partial reduce + residual: out = x + p0 + p1.
// ---------------------------------------------------------------------------
__global__ __launch_bounds__(256) void out_reduce(
    const float* __restrict__ x, const float* __restrict__ part,  // [2][MR][DM]
    float* __restrict__ out) {
  const int i = blockIdx.x * 256 + threadIdx.x;   // MR*DM/4 = 524288
  float4 a  = ((const float4*)x)[i];
  float4 p0 = ((const float4*)part)[i];
  float4 p1 = ((const float4*)(part + (size_t)MR * DM))[i];
  ((float4*)out)[i] = make_float4(a.x + p0.x + p1.x, a.y + p0.y + p1.y,
                                  a.z + p0.z + p1.z, a.w + p0.w + p1.w);
}

// ---------------------------------------------------------------------------
// Depthwise causal conv1d (width 4) + bias + SiLU, 8 channels per thread.
// ---------------------------------------------------------------------------
__global__ __launch_bounds__(256) void conv_silu_kernel(
    const _Float16* __restrict__ xin, const float* __restrict__ cw,
    const float* __restrict__ cb, _Float16* __restrict__ xc) {
  const int idx = blockIdx.x * 256 + threadIdx.x;   // 0 .. MR*DI/8-1
  const int d8 = idx & (DI / 8 - 1);
  const int ml = idx >> 8;
  const int l  = ml & (LL - 1);
  const int d0 = d8 * 8;
  half8 xr[4];
  const half8 zero = {0, 0, 0, 0, 0, 0, 0, 0};
#pragma unroll
  for (int k = 0; k < 4; k++) {
    const int lp = l - 3 + k;
    xr[k] = (lp >= 0) ? *(const half8*)&xin[(size_t)(ml - 3 + k) * DI + d0] : zero;
  }
  half8 o;
#pragma unroll
  for (int j = 0; j < 8; j++) {
    float acc = cb[d0 + j];
#pragma unroll
    for (int k = 0; k < 4; k++)
      acc += (float)xr[k][j] * cw[(d0 + j) * 4 + k];
    o[j] = (_Float16)(acc / (1.f + __expf(-acc)));
  }
  *(half8*)&xc[(size_t)ml * DI + d0] = o;
}

// ---------------------------------------------------------------------------
// Load per-channel A row; detect S4D-real init a[s] == -(s+1) (uniform).
// ---------------------------------------------------------------------------
__device__ __forceinline__ bool load_a(const float* __restrict__ A_log, int d,
                                       float* a) {
  const float4* Ap = (const float4*)(A_log + (size_t)d * DS);
  bool fast = true;
#pragma unroll
  for (int i = 0; i < 4; i++) {
    float4 v = Ap[i];
    a[4 * i + 0] = -__expf(v.x); a[4 * i + 1] = -__expf(v.y);
    a[4 * i + 2] = -__expf(v.z); a[4 * i + 3] = -__expf(v.w);
  }
#pragma unroll
  for (int s = 0; s < DS; s++)
    fast = fast && (fabsf(a[s] + (float)(s + 1)) < 1e-4f);
  return fast;
}

// ---------------------------------------------------------------------------
// Chunked selective scan, phase 1: per-(b,chunk) local scan with h=0 init.
// Fast path: exp(dt*a[s]) = r^(s+1), r = exp(-dt)  (1 exp + 15 mul vs 16 exp).
// ---------------------------------------------------------------------------
__global__ __launch_bounds__(256) void scan_phase1(
    const _Float16* __restrict__ xc,  // x_conv (MR x DI) f16
    const float* __restrict__ xdbl,   // (MR x 96)
    const float* __restrict__ dtm,    // dt after softplus (MR x DI) f32
    const float* __restrict__ A_log,
    float* __restrict__ HE,           // (NB*NC*DS) x DI
    float* __restrict__ SA) {         // (NB*NC) x DI
  __shared__ float Bs[CL][DS];
  const int bi = blockIdx.x;
  const int dblk = bi & 7;
  const int c = (bi >> 3) & (NC - 1);
  const int b = bi >> 8;
  const int t = threadIdx.x;
  const int d = dblk * 256 + t;
  const int mlbase = b * LL + c * CL;

  for (int i = t; i < CL * DS; i += 256) {
    int tt = i >> 4, s = i & 15;
    Bs[tt][s] = xdbl[(size_t)(mlbase + tt) * XDBL + DTR + s];
  }

  float a[DS];
  const bool fast = load_a(A_log, d, a);
  float h[DS];
#pragma unroll
  for (int s = 0; s < DS; s++) h[s] = 0.f;
  float S = 0.f;
  __syncthreads();

  if (fast) {
    for (int tt = 0; tt < CL; tt++) {
      const size_t ml = mlbase + tt;
      const float dtv = dtm[ml * DI + d];
      const float u   = (float)xc[ml * DI + d];
      const float du  = dtv * u;
      S += dtv;
      const float r = __expf(-dtv);
      float P = 1.f;
#pragma unroll
      for (int s = 0; s < DS; s++) {
        P *= r;
        h[s] = P * h[s] + du * Bs[tt][s];
      }
    }
  } else {
    for (int tt = 0; tt < CL; tt++) {
      const size_t ml = mlbase + tt;
      const float dtv = dtm[ml * DI + d];
      const float u   = (float)xc[ml * DI + d];
      const float du  = dtv * u;
      S += dtv;
#pragma unroll
      for (int s = 0; s < DS; s++)
        h[s] = __expf(dtv * a[s]) * h[s] + du * Bs[tt][s];
    }
  }
  const size_t base = ((size_t)(b * NC + c) * DS) * DI + d;
#pragma unroll
  for (int s = 0; s < DS; s++) HE[base + (size_t)s * DI] = h[s];
  SA[(size_t)(b * NC + c) * DI + d] = S;
}

// ---------------------------------------------------------------------------
// Phase 2: sequential combine over chunk aggregates; HE becomes carry-in.
// ---------------------------------------------------------------------------
__global__ __launch_bounds__(256) void scan_phase2(
    const float* __restrict__ A_log,
    const float* __restrict__ SA,
    float* __restrict__ HE) {
  const int idx = blockIdx.x * 256 + threadIdx.x;  // NB*DS*DI
  const int d = idx & (DI - 1);
  const int s = (idx >> 11) & (DS - 1);
  const int b = idx >> 15;
  const float a = -__expf(A_log[(size_t)d * DS + s]);
  float Hc = 0.f;
  for (int c = 0; c < NC; c++) {
    const size_t o = ((size_t)(b * NC + c) * DS + s) * DI + d;
    const float he = HE[o];
    const float P = __expf(a * SA[(size_t)(b * NC + c) * DI + d]);
    HE[o] = Hc;
    Hc = P * Hc + he;
  }
}

// ---------------------------------------------------------------------------
// Phase 3: re-run chunks with carry-in; fuse y = (sum_s h*C + u*D)*silu(z).
// ---------------------------------------------------------------------------
__global__ __launch_bounds__(256) void scan_phase3(
    const _Float16* __restrict__ xc,
    const float* __restrict__ xdbl,
    const float* __restrict__ dtm,      // f32
    const _Float16* __restrict__ zbuf,  // z (MR x DI) f16
    const float* __restrict__ A_log,
    const float* __restrict__ Dvec,
    const float* __restrict__ HE,
    _Float16* __restrict__ y) {         // (MR x DI) f16
  __shared__ float Bs[CL][DS];
  __shared__ float Cs[CL][DS];
  const int bi = blockIdx.x;
  const int dblk = bi & 7;
  const int c = (bi >> 3) & (NC - 1);
  const int b = bi >> 8;
  const int t = threadIdx.x;
  const int d = dblk * 256 + t;
  const int mlbase = b * LL + c * CL;

  for (int i = t; i < CL * DS; i += 256) {
    int tt = i >> 4, s = i & 15;
    const size_t ro = (size_t)(mlbase + tt) * XDBL + DTR + s;
    Bs[tt][s] = xdbl[ro];
    Cs[tt][s] = xdbl[ro + DS];
  }

  float a[DS];
  const bool fast = load_a(A_log, d, a);
  float h[DS];
  const size_t base = ((size_t)(b * NC + c) * DS) * DI + d;
#pragma unroll
  for (int s = 0; s < DS; s++) h[s] = HE[base + (size_t)s * DI];
  const float Dv = Dvec[d];
  __syncthreads();

  if (fast) {
    for (int tt = 0; tt < CL; tt++) {
      const size_t ml = mlbase + tt;
      const float dtv = dtm[ml * DI + d];
      const float u   = (float)xc[ml * DI + d];
      const float du  = dtv * u;
      const float r = __expf(-dtv);
      float P = 1.f, p = 0.f;
#pragma unroll
      for (int s = 0; s < DS; s++) {
        P *= r;
        h[s] = P * h[s] + du * Bs[tt][s];
        p += h[s] * Cs[tt][s];
      }
      const float zv = (float)zbuf[ml * DI + d];
      const float sil = zv / (1.f + __expf(-zv));
      y[ml * DI + d] = (_Float16)((p + u * Dv) * sil);
    }
  } else {
    for (int tt = 0; tt < CL; tt++) {
      const size_t ml = mlbase + tt;
      const float dtv = dtm[ml * DI + d];
      const float u   = (float)xc[ml * DI + d];
      const float du  = dtv * u;
      float p = 0.f;
#pragma unroll
      for (int s = 0; s < DS; s++) {
        h[s] = __expf(dtv * a[s]) * h[s] + du * Bs[tt][s];
        p += h[s] * Cs[tt][s];
      }
      const float zv = (float)zbuf[ml * DI + d];
      const float sil = zv / (1.f + __expf(-zv));
      y[ml * DI + d] = (_Float16)((p + u * Dv) * sil);
    }
  }
}

// ---------------------------------------------------------------------------
// Launch
// ---------------------------------------------------------------------------
extern "C" void kernel_launch(void* const* d_in, const int* in_sizes, int n_in,
                              void* d_out, int out_size, void* d_ws, size_t ws_size,
                              hipStream_t stream) {
  const float* x         = (const float*)d_in[0];
  const float* ln_w      = (const float*)d_in[1];
  const float* ln_b      = (const float*)d_in[2];
  const float* in_proj_w = (const float*)d_in[3];   // (4096, 1024)
  const float* conv_w    = (const float*)d_in[4];   // (2048, 1, 4)
  const float* conv_b    = (const float*)d_in[5];
  const float* x_proj_w  = (const float*)d_in[6];   // (96, 2048)
  const float* dt_proj_w = (const float*)d_in[7];   // (2048, 64)
  const float* dt_proj_b = (const float*)d_in[8];
  const float* A_log     = (const float*)d_in[9];   // (2048, 16)
  const float* Dvec      = (const float*)d_in[10];
  const float* out_proj_w= (const float*)d_in[11];  // (1024, 2048)
  float* out = (float*)d_out;

  // workspace layout (bytes; total ~82 MB)
  char* ws = (char*)d_ws;
  _Float16* h_h     = (_Float16*)ws;                 //  4 MB (MR*DM) — dead after in_proj
  _Float16* xin_h   = (_Float16*)(ws + 4194304);     //  8 MB — dead after conv
  _Float16* y_h     = xin_h;                         //  aliases xin
  _Float16* z_h     = (_Float16*)(ws + 12582912);    //  8 MB
  _Float16* xc_h    = (_Float16*)(ws + 20971520);    //  8 MB
  float*    dtb     = (float*)   (ws + 29360128);    // 16 MB (MR*DI f32) — dead after p3
  float*    out_part= dtb;                           // 16 MB (2 x MR x DM f32), aliases dtb
  float*    x_dbl   = (float*)   (ws + 46137344);    //  0.75 MB
  float*    SA      = (float*)   (ws + 46923776);    //  0.5 MB
  _Float16* dtr_h   = (_Float16*)(ws + 47448064);    //  0.25 MB
  float*    HE      = (float*)   (ws + 47710208);    //  8 MB
  _Float16* w_in_h  = (_Float16*)(ws + 56098816);    //  8 MB
  _Float16* w_out_h = (_Float16*)(ws + 64487424);    //  4 MB
  _Float16* w_xp_h  = (_Float16*)(ws + 68681728);    //  0.375 MB
  _Float16* w_dt_h  = (_Float16*)(ws + 69074944);    //  0.25 MB
  float*    xp_part = (float*)   (ws + 69337088);    // 12.6 MB (16 x MR x 96 f32)

  // 0+1. fused: layernorm + weight f2h
  front_kernel<<<MR + 6464, 256, 0, stream>>>(
      x, ln_w, ln_b, in_proj_w, out_proj_w, x_proj_w, dt_proj_w,
      h_h, w_in_h, w_out_h, w_xp_h, w_dt_h);

  // 2. in_proj: N=4096, tile 128x128 -> 512 blocks (2/CU), fat K-steps
  gemm_mfma<0, 128><<<dim3(2 * DI / 128, MR / 128, 1), 256, 0, stream>>>(
      h_h, w_in_h, xin_h, z_h, nullptr, 0, MR, 2 * DI, DM, DM);

  // 3. conv + silu -> xc_h (f16), 8 channels/thread
  conv_silu_kernel<<<(MR * DI / 8) / 256, 256, 0, stream>>>(xin_h, conv_w, conv_b, xc_h);

  // 4. x_proj: tile 128x96, split-K 16 -> streaming partials (no atomics)
  gemm_mfma<4, 96><<<dim3(1, MR / 128, 16), 256, 0, stream>>>(
      xc_h, w_xp_h, xp_part, nullptr, nullptr, XDBL, MR, XDBL, DI, DI / 16);
  xproj_reduce<<<(MR * XDBL) / 256, 256, 0, stream>>>(xp_part, x_dbl, dtr_h);

  // 5. dt: MFMA + fast softplus -> f32 dtb (tile 128x64), K=64
  gemm_mfma<1, 64><<<dim3(DI / 64, MR / 128, 1), 256, 0, stream>>>(
      dtr_h, w_dt_h, dtb, nullptr, dt_proj_b, DI, MR, DI, DTR, DTR);

  // 6. chunked selective scan
  scan_phase1<<<NB * NC * (DI / 256), 256, 0, stream>>>(
      xc_h, x_dbl, dtb, A_log, HE, SA);
  scan_phase2<<<(NB * DS * DI) / 256, 256, 0, stream>>>(A_log, SA, HE);
  scan_phase3<<<NB * NC * (DI / 256), 256, 0, stream>>>(
      xc_h, x_dbl, dtb, z_h, A_log, Dvec, HE, y_h);

  // 7. out_proj: tile 128x64, split-K 2 -> 512 blocks (2/CU), streaming
  //    partials into dead dtb, then out = x + p0 + p1
  gemm_mfma<4, 64><<<dim3(DM / 64, MR / 128, 2), 256, 0, stream>>>(
      y_h, w_out_h, out_part, nullptr, nullptr, DM, MR, DM, DI, DI / 2);
  out_reduce<<<(MR * DM / 4) / 256, 256, 0, stream>>>(x, out_part, out);
}

// Round 12
// 227.448 us; speedup vs baseline: 1.1106x; 1.0148x over previous
//
#include <hip/hip_runtime.h>
#include <hip/hip_bf16.h>
#include <math.h>

// Problem constants (from reference)
#define DM   1024        // d_model
#define DI   2048        // d_inner
#define DS   16          // d_state
#define DTR  64          // dt_rank
#define NB   2           // batch
#define LL   1024        // seq len
#define MR   (NB*LL)     // 2048 rows (b*l flattened)
#define XDBL 96          // dt_rank + 2*d_state
#define NC   32          // scan chunks
#define CL   32          // chunk length (NC*CL == LL)

typedef _Float16 half8  __attribute__((ext_vector_type(8)));
typedef _Float16 half4v __attribute__((ext_vector_type(4)));
typedef float    floatx4 __attribute__((ext_vector_type(4)));

__device__ __forceinline__ void gload_lds16(const void* g, void* l) {
  __builtin_amdgcn_global_load_lds(
      (const __attribute__((address_space(1))) void*)g,
      (__attribute__((address_space(3))) void*)l, 16, 0, 0);
}

// ---------------------------------------------------------------------------
// Front kernel: LN (blocks 0..2047) + weight f2h.
// ---------------------------------------------------------------------------
__global__ __launch_bounds__(256) void front_kernel(
    const float* __restrict__ x, const float* __restrict__ ln_w,
    const float* __restrict__ ln_b,
    const float* __restrict__ w_in, const float* __restrict__ w_out,
    const float* __restrict__ w_xp, const float* __restrict__ w_dt,
    _Float16* __restrict__ h_h,
    _Float16* __restrict__ w_in_h, _Float16* __restrict__ w_out_h,
    _Float16* __restrict__ w_xp_h, _Float16* __restrict__ w_dt_h) {
  const int blk = blockIdx.x;
  if (blk < MR) {
    __shared__ float sA[4], sB[4];
    const float* xr = x + (size_t)blk * DM;
    float s = 0.f, ss = 0.f;
    for (int i = threadIdx.x; i < DM; i += 256) {
      float v = xr[i];
      s += v; ss += v * v;
    }
    for (int o = 32; o > 0; o >>= 1) {
      s  += __shfl_down(s, o, 64);
      ss += __shfl_down(ss, o, 64);
    }
    const int wid = threadIdx.x >> 6, lid = threadIdx.x & 63;
    if (lid == 0) { sA[wid] = s; sB[wid] = ss; }
    __syncthreads();
    if (threadIdx.x == 0) {
      float S = sA[0] + sA[1] + sA[2] + sA[3];
      float SS = sB[0] + sB[1] + sB[2] + sB[3];
      float mu = S / DM;
      sA[0] = mu;
      sB[0] = rsqrtf(SS / DM - mu * mu + 1e-5f);
    }
    __syncthreads();
    const float mu = sA[0], rs = sB[0];
    for (int i = threadIdx.x; i < DM; i += 256)
      h_h[(size_t)blk * DM + i] = (_Float16)((xr[i] - mu) * rs * ln_w[i] + ln_b[i]);
    return;
  }
  int i = (blk - MR) * 256 + threadIdx.x;
  const int N0 = 1048576, N1 = 524288, N2 = 49152, N3 = 32768;
  const float* s; _Float16* d; int off;
  if (i < N0)            { s = w_in;  d = w_in_h;  off = i; }
  else if (i < N0+N1)    { s = w_out; d = w_out_h; off = i - N0; }
  else if (i < N0+N1+N2) { s = w_xp;  d = w_xp_h;  off = i - N0 - N1; }
  else if (i < N0+N1+N2+N3) { s = w_dt; d = w_dt_h; off = i - N0 - N1 - N2; }
  else return;
  float4 v = ((const float4*)s)[off];
  half4v h = {(_Float16)v.x, (_Float16)v.y, (_Float16)v.z, (_Float16)v.w};
  ((half4v*)d)[off] = h;
}

// ---------------------------------------------------------------------------
// MFMA f16 GEMM, double-buffered LDS pipeline + XOR bank swizzle.
// C[m,n] = sum_k A[m,k]*W[n,k], fp32 accumulate. Tile 128 x TN, BK=32,
// 4 waves each 64 x TN/2.
// r10/r11 lessons: bank conflicts were NOT the limiter; per-K-step latency
// quantum (~500 cyc) is. Fewer, fatter step-slots win (TN=128: 16 MFMA per
// wave-step, 8 B LDS read per MFMA). r7 lesson: f16 epilogue stores are fine
// (EPI0 proves it); libm softplus slow path (SGPR=112) was the 70us bug —
// always use __logf/__expf.
// EPI 0: dual f16 store (n<DI -> Cv, else C2v; compact DI-wide rows)
// EPI 4: f16 partial store at Cv + blockIdx.z*M*ldc (split-K, no atomics)
// EPI 5: f16 store softplus(acc + extra[n])  [fast-math]
// ---------------------------------------------------------------------------
template <int EPI, int TN>
__global__ __launch_bounds__(256) void gemm_mfma(
    const _Float16* __restrict__ A,   // [M][K]
    const _Float16* __restrict__ W,   // [N][K]
    void* __restrict__ Cv, void* __restrict__ C2v,
    const float* __restrict__ extra, int ldc,
    int M, int N, int K, int kchunk) {
  constexpr int NT = (TN + 31) / 32;   // 16-col tiles per wave (1,2,3,4)
  constexpr int WSLOT = TN / 16;       // W staging slots (512 halves each)
  __shared__ alignas(16) _Float16 As[2][128 * 32];
  __shared__ alignas(16) _Float16 Ws[2][TN * 32];
  const int t = threadIdx.x;
  const int wave = t >> 6, lane = t & 63;
  const int m0 = blockIdx.y * 128, n0 = blockIdx.x * TN;
  const int k_beg = blockIdx.z * kchunk;
  const int nk = kchunk >> 5;
  const int wm = (wave >> 1) * 64, wn = (wave & 1) * (TN / 2);
  floatx4 acc[4][NT];
#pragma unroll
  for (int i = 0; i < 4; i++)
#pragma unroll
    for (int j = 0; j < NT; j++) acc[i][j] = {0.f, 0.f, 0.f, 0.f};

  const int fr = lane & 15;     // row within 16-tile
  const int kc8 = lane >> 4;    // logical 8-half k-chunk this lane consumes
  const int kp = (kc8 ^ ((fr >> 1) & 3)) * 8;   // swizzled physical chunk (halves)

  auto stage = [&](int buf, int k0) {
    for (int sl = wave; sl < 8; sl += 4) {
      const int idx = sl * 64 + lane;
      const int row = idx >> 2;
      const int kc = (idx & 3) ^ ((row >> 1) & 3);   // XOR-swizzled fetch
      gload_lds16(A + (size_t)(m0 + row) * K + k0 + kc * 8, &As[buf][sl * 512]);
    }
    for (int sl = wave; sl < WSLOT; sl += 4) {
      const int idx = sl * 64 + lane;
      const int row = idx >> 2;
      const int kc = (idx & 3) ^ ((row >> 1) & 3);
      const int wrow = (n0 + row < N) ? row : 0;   // safety clamp
      gload_lds16(W + (size_t)(n0 + wrow) * K + k0 + kc * 8, &Ws[buf][sl * 512]);
    }
  };

  stage(0, k_beg);
  int cur = 0;
  for (int ki = 0; ki < nk; ki++) {
    __syncthreads();                       // stage(cur) complete; prior reads done
    if (ki + 1 < nk) stage(cur ^ 1, k_beg + ((ki + 1) << 5));   // async prefetch
    half8 af[4], wf[NT];
#pragma unroll
    for (int i = 0; i < 4; i++)
      af[i] = *(const half8*)&As[cur][(wm + i * 16 + fr) * 32 + kp];
#pragma unroll
    for (int j = 0; j < NT; j++)
      wf[j] = *(const half8*)&Ws[cur][(wn + j * 16 + fr) * 32 + kp];
#pragma unroll
    for (int i = 0; i < 4; i++)
#pragma unroll
      for (int j = 0; j < NT; j++)
        acc[i][j] = __builtin_amdgcn_mfma_f32_16x16x32_f16(af[i], wf[j], acc[i][j], 0, 0, 0);
    cur ^= 1;
  }

  // epilogue: C/D layout col = lane&15, row = (lane>>4)*4 + reg
  const int col = lane & 15, rowq = lane >> 4;
#pragma unroll
  for (int i = 0; i < 4; i++) {
#pragma unroll
    for (int j = 0; j < NT; j++) {
      const int n = n0 + wn + j * 16 + col;
      if (n < N) {
#pragma unroll
        for (int r = 0; r < 4; r++) {
          const int m = m0 + wm + i * 16 + rowq * 4 + r;
          float v = acc[i][j][r];
          if (EPI == 0) {
            if (n < DI) ((_Float16*)Cv )[(size_t)m * DI + n]      = (_Float16)v;
            else        ((_Float16*)C2v)[(size_t)m * DI + n - DI] = (_Float16)v;
          } else if (EPI == 4) {
            ((_Float16*)Cv)[((size_t)blockIdx.z * M + m) * ldc + n] = (_Float16)v;
          } else if (EPI == 5) {
            v += extra[n];
            v = (v > 20.f) ? v : __logf(1.f + __expf(v));   // fast softplus
            ((_Float16*)Cv)[(size_t)m * ldc + n] = (_Float16)v;
          }
        }
      }
    }
  }
}

// ---------------------------------------------------------------------------
// x_proj partial reduce (f16 partials): x_dbl = sum_z part[z], emit dtr f16.
// ---------------------------------------------------------------------------
__global__ __launch_bounds__(256) void xproj_reduce(
    const _Float16* __restrict__ part,   // [16][MR][XDBL] f16
    float* __restrict__ x_dbl, _Float16* __restrict__ dtr) {
  const int idx = blockIdx.x * 256 + threadIdx.x;   // MR*XDBL = 196608
  const int m = idx / XDBL, c = idx - m * XDBL;
  float s = 0.f;
#pragma unroll
  for (int z = 0; z < 16; z++) s += (float)part[(size_t)z * (MR * XDBL) + idx];
  x_dbl[idx] = s;
  if (c < DTR) dtr[m * DTR + c] = (_Float16)s;
}

// ---------------------------------------------------------------------------
// out_proj partial reduce + residual: out = x + sum of 4 f16 partials.
// ---------------------------------------------------------------------------
__global__ __launch_bounds__(256) void out_reduce(
    const float* __restrict__ x, const _Float16* __restrict__ part,  // [4][MR][DM]
    float* __restrict__ out) {
  const int i = blockIdx.x * 256 + threadIdx.x;   // MR*DM/4 = 524288
  float4 a = ((const float4*)x)[i];
#pragma unroll
  for (int z = 0; z < 4; z++) {
    half4v p = ((const half4v*)(part + (size_t)z * MR * DM))[i];
    a.x += (float)p.x; a.y += (float)p.y; a.z += (float)p.z; a.w += (float)p.w;
  }
  ((float4*)out)[i] = a;
}

// ---------------------------------------------------------------------------
// Depthwise causal conv1d (width 4) + bias + SiLU, 8 channels per thread.
// ---------------------------------------------------------------------------
__global__ __launch_bounds__(256) void conv_silu_kernel(
    const _Float16* __restrict__ xin, const float* __restrict__ cw,
    const float* __restrict__ cb, _Float16* __restrict__ xc) {
  const int idx = blockIdx.x * 256 + threadIdx.x;   // 0 .. MR*DI/8-1
  const int d8 = idx & (DI / 8 - 1);
  const int ml = idx >> 8;
  const int l  = ml & (LL - 1);
  const int d0 = d8 * 8;
  half8 xr[4];
  const half8 zero = {0, 0, 0, 0, 0, 0, 0, 0};
#pragma unroll
  for (int k = 0; k < 4; k++) {
    const int lp = l - 3 + k;
    xr[k] = (lp >= 0) ? *(const half8*)&xin[(size_t)(ml - 3 + k) * DI + d0] : zero;
  }
  half8 o;
#pragma unroll
  for (int j = 0; j < 8; j++) {
    float acc = cb[d0 + j];
#pragma unroll
    for (int k = 0; k < 4; k++)
      acc += (float)xr[k][j] * cw[(d0 + j) * 4 + k];
    o[j] = (_Float16)(acc / (1.f + __expf(-acc)));
  }
  *(half8*)&xc[(size_t)ml * DI + d0] = o;
}

// ---------------------------------------------------------------------------
// Load per-channel A row; detect S4D-real init a[s] == -(s+1) (uniform).
// ---------------------------------------------------------------------------
__device__ __forceinline__ bool load_a(const float* __restrict__ A_log, int d,
                                       float* a) {
  const float4* Ap = (const float4*)(A_log + (size_t)d * DS);
  bool fast = true;
#pragma unroll
  for (int i = 0; i < 4; i++) {
    float4 v = Ap[i];
    a[4 * i + 0] = -__expf(v.x); a[4 * i + 1] = -__expf(v.y);
    a[4 * i + 2] = -__expf(v.z); a[4 * i + 3] = -__expf(v.w);
  }
#pragma unroll
  for (int s = 0; s < DS; s++)
    fast = fast && (fabsf(a[s] + (float)(s + 1)) < 1e-4f);
  return fast;
}

// ---------------------------------------------------------------------------
// Chunked selective scan, phase 1: per-(b,chunk) local scan with h=0 init.
// Fast path: exp(dt*a[s]) = r^(s+1), r = exp(-dt)  (1 exp + 15 mul vs 16 exp).
// ---------------------------------------------------------------------------
__global__ __launch_bounds__(256) void scan_phase1(
    const _Float16* __restrict__ xc,  // x_conv (MR x DI) f16
    const float* __restrict__ xdbl,   // (MR x 96)
    const _Float16* __restrict__ dtm, // dt after softplus (MR x DI) f16
    const float* __restrict__ A_log,
    float* __restrict__ HE,           // (NB*NC*DS) x DI
    float* __restrict__ SA) {         // (NB*NC) x DI
  __shared__ float Bs[CL][DS];
  const int bi = blockIdx.x;
  const int dblk = bi & 7;
  const int c = (bi >> 3) & (NC - 1);
  const int b = bi >> 8;
  const int t = threadIdx.x;
  const int d = dblk * 256 + t;
  const int mlbase = b * LL + c * CL;

  for (int i = t; i < CL * DS; i += 256) {
    int tt = i >> 4, s = i & 15;
    Bs[tt][s] = xdbl[(size_t)(mlbase + tt) * XDBL + DTR + s];
  }

  float a[DS];
  const bool fast = load_a(A_log, d, a);
  float h[DS];
#pragma unroll
  for (int s = 0; s < DS; s++) h[s] = 0.f;
  float S = 0.f;
  __syncthreads();

  if (fast) {
    for (int tt = 0; tt < CL; tt++) {
      const size_t ml = mlbase + tt;
      const float dtv = (float)dtm[ml * DI + d];
      const float u   = (float)xc[ml * DI + d];
      const float du  = dtv * u;
      S += dtv;
      const float r = __expf(-dtv);
      float P = 1.f;
#pragma unroll
      for (int s = 0; s < DS; s++) {
        P *= r;
        h[s] = P * h[s] + du * Bs[tt][s];
      }
    }
  } else {
    for (int tt = 0; tt < CL; tt++) {
      const size_t ml = mlbase + tt;
      const float dtv = (float)dtm[ml * DI + d];
      const float u   = (float)xc[ml * DI + d];
      const float du  = dtv * u;
      S += dtv;
#pragma unroll
      for (int s = 0; s < DS; s++)
        h[s] = __expf(dtv * a[s]) * h[s] + du * Bs[tt][s];
    }
  }
  const size_t base = ((size_t)(b * NC + c) * DS) * DI + d;
#pragma unroll
  for (int s = 0; s < DS; s++) HE[base + (size_t)s * DI] = h[s];
  SA[(size_t)(b * NC + c) * DI + d] = S;
}

// ---------------------------------------------------------------------------
// Phase 2: sequential combine over chunk aggregates; HE becomes carry-in.
// ---------------------------------------------------------------------------
__global__ __launch_bounds__(256) void scan_phase2(
    const float* __restrict__ A_log,
    const float* __restrict__ SA,
    float* __restrict__ HE) {
  const int idx = blockIdx.x * 256 + threadIdx.x;  // NB*DS*DI
  const int d = idx & (DI - 1);
  const int s = (idx >> 11) & (DS - 1);
  const int b = idx >> 15;
  const float a = -__expf(A_log[(size_t)d * DS + s]);
  float Hc = 0.f;
  for (int c = 0; c < NC; c++) {
    const size_t o = ((size_t)(b * NC + c) * DS + s) * DI + d;
    const float he = HE[o];
    const float P = __expf(a * SA[(size_t)(b * NC + c) * DI + d]);
    HE[o] = Hc;
    Hc = P * Hc + he;
  }
}

// ---------------------------------------------------------------------------
// Phase 3: re-run chunks with carry-in; fuse y = (sum_s h*C + u*D)*silu(z).
// ---------------------------------------------------------------------------
__global__ __launch_bounds__(256) void scan_phase3(
    const _Float16* __restrict__ xc,
    const float* __restrict__ xdbl,
    const _Float16* __restrict__ dtm,   // f16
    const _Float16* __restrict__ zbuf,  // z (MR x DI) f16
    const float* __restrict__ A_log,
    const float* __restrict__ Dvec,
    const float* __restrict__ HE,
    _Float16* __restrict__ y) {         // (MR x DI) f16
  __shared__ float Bs[CL][DS];
  __shared__ float Cs[CL][DS];
  const int bi = blockIdx.x;
  const int dblk = bi & 7;
  const int c = (bi >> 3) & (NC - 1);
  const int b = bi >> 8;
  const int t = threadIdx.x;
  const int d = dblk * 256 + t;
  const int mlbase = b * LL + c * CL;

  for (int i = t; i < CL * DS; i += 256) {
    int tt = i >> 4, s = i & 15;
    const size_t ro = (size_t)(mlbase + tt) * XDBL + DTR + s;
    Bs[tt][s] = xdbl[ro];
    Cs[tt][s] = xdbl[ro + DS];
  }

  float a[DS];
  const bool fast = load_a(A_log, d, a);
  float h[DS];
  const size_t base = ((size_t)(b * NC + c) * DS) * DI + d;
#pragma unroll
  for (int s = 0; s < DS; s++) h[s] = HE[base + (size_t)s * DI];
  const float Dv = Dvec[d];
  __syncthreads();

  if (fast) {
    for (int tt = 0; tt < CL; tt++) {
      const size_t ml = mlbase + tt;
      const float dtv = (float)dtm[ml * DI + d];
      const float u   = (float)xc[ml * DI + d];
      const float du  = dtv * u;
      const float r = __expf(-dtv);
      float P = 1.f, p = 0.f;
#pragma unroll
      for (int s = 0; s < DS; s++) {
        P *= r;
        h[s] = P * h[s] + du * Bs[tt][s];
        p += h[s] * Cs[tt][s];
      }
      const float zv = (float)zbuf[ml * DI + d];
      const float sil = zv / (1.f + __expf(-zv));
      y[ml * DI + d] = (_Float16)((p + u * Dv) * sil);
    }
  } else {
    for (int tt = 0; tt < CL; tt++) {
      const size_t ml = mlbase + tt;
      const float dtv = (float)dtm[ml * DI + d];
      const float u   = (float)xc[ml * DI + d];
      const float du  = dtv * u;
      float p = 0.f;
#pragma unroll
      for (int s = 0; s < DS; s++) {
        h[s] = __expf(dtv * a[s]) * h[s] + du * Bs[tt][s];
        p += h[s] * Cs[tt][s];
      }
      const float zv = (float)zbuf[ml * DI + d];
      const float sil = zv / (1.f + __expf(-zv));
      y[ml * DI + d] = (_Float16)((p + u * Dv) * sil);
    }
  }
}

// ---------------------------------------------------------------------------
// Launch
// ---------------------------------------------------------------------------
extern "C" void kernel_launch(void* const* d_in, const int* in_sizes, int n_in,
                              void* d_out, int out_size, void* d_ws, size_t ws_size,
                              hipStream_t stream) {
  const float* x         = (const float*)d_in[0];
  const float* ln_w      = (const float*)d_in[1];
  const float* ln_b      = (const float*)d_in[2];
  const float* in_proj_w = (const float*)d_in[3];   // (4096, 1024)
  const float* conv_w    = (const float*)d_in[4];   // (2048, 1, 4)
  const float* conv_b    = (const float*)d_in[5];
  const float* x_proj_w  = (const float*)d_in[6];   // (96, 2048)
  const float* dt_proj_w = (const float*)d_in[7];   // (2048, 64)
  const float* dt_proj_b = (const float*)d_in[8];
  const float* A_log     = (const float*)d_in[9];   // (2048, 16)
  const float* Dvec      = (const float*)d_in[10];
  const float* out_proj_w= (const float*)d_in[11];  // (1024, 2048)
  float* out = (float*)d_out;

  // workspace layout (bytes; total ~75.6 MB)
  char* ws = (char*)d_ws;
  _Float16* h_h      = (_Float16*)ws;                 //  4 MB — dead after in_proj
  _Float16* xin_h    = (_Float16*)(ws + 4194304);     //  8 MB — dead after conv
  _Float16* y_h      = xin_h;                         //  aliases xin
  _Float16* z_h      = (_Float16*)(ws + 12582912);    //  8 MB
  _Float16* xc_h     = (_Float16*)(ws + 20971520);    //  8 MB
  _Float16* dtb_h    = (_Float16*)(ws + 29360128);    //  8 MB f16 — dead after p3
  _Float16* out_part = dtb_h;                         // 16 MB (4 x MR*DM f16), aliases dtb+spare
  float*    x_dbl    = (float*)   (ws + 46137344);    //  0.75 MB
  float*    SA       = (float*)   (ws + 46923776);    //  0.5 MB
  _Float16* dtr_h    = (_Float16*)(ws + 47448064);    //  0.25 MB
  float*    HE       = (float*)   (ws + 47710208);    //  8 MB
  _Float16* w_in_h   = (_Float16*)(ws + 56098816);    //  8 MB
  _Float16* w_out_h  = (_Float16*)(ws + 64487424);    //  4 MB
  _Float16* w_xp_h   = (_Float16*)(ws + 68681728);    //  0.375 MB
  _Float16* w_dt_h   = (_Float16*)(ws + 69074944);    //  0.25 MB
  _Float16* xp_part  = (_Float16*)(ws + 69337088);    //  6 MB (16 x MR x 96 f16)

  // 0+1. fused: layernorm + weight f2h
  front_kernel<<<MR + 6464, 256, 0, stream>>>(
      x, ln_w, ln_b, in_proj_w, out_proj_w, x_proj_w, dt_proj_w,
      h_h, w_in_h, w_out_h, w_xp_h, w_dt_h);

  // 2. in_proj: N=4096, tile 128x128 -> 512 blocks (2/CU), fat K-steps
  gemm_mfma<0, 128><<<dim3(2 * DI / 128, MR / 128, 1), 256, 0, stream>>>(
      h_h, w_in_h, xin_h, z_h, nullptr, 0, MR, 2 * DI, DM, DM);

  // 3. conv + silu -> xc_h (f16), 8 channels/thread
  conv_silu_kernel<<<(MR * DI / 8) / 256, 256, 0, stream>>>(xin_h, conv_w, conv_b, xc_h);

  // 4. x_proj: tile 128x96, split-K 16 -> f16 streaming partials
  gemm_mfma<4, 96><<<dim3(1, MR / 128, 16), 256, 0, stream>>>(
      xc_h, w_xp_h, xp_part, nullptr, nullptr, XDBL, MR, XDBL, DI, DI / 16);
  xproj_reduce<<<(MR * XDBL) / 256, 256, 0, stream>>>(xp_part, x_dbl, dtr_h);

  // 5. dt: MFMA + fast softplus -> f16 dtb (tile 128x64), K=64
  gemm_mfma<5, 64><<<dim3(DI / 64, MR / 128, 1), 256, 0, stream>>>(
      dtr_h, w_dt_h, dtb_h, nullptr, dt_proj_b, DI, MR, DI, DTR, DTR);

  // 6. chunked selective scan
  scan_phase1<<<NB * NC * (DI / 256), 256, 0, stream>>>(
      xc_h, x_dbl, dtb_h, A_log, HE, SA);
  scan_phase2<<<(NB * DS * DI) / 256, 256, 0, stream>>>(A_log, SA, HE);
  scan_phase3<<<NB * NC * (DI / 256), 256, 0, stream>>>(
      xc_h, x_dbl, dtb_h, z_h, A_log, Dvec, HE, y_h);

  // 7. out_proj: tile 128x128, split-K 4 -> 512 blocks (2/CU), f16 partials
  //    (alias dead dtb region), then out = x + sum(partials)
  gemm_mfma<4, 128><<<dim3(DM / 128, MR / 128, 4), 256, 0, stream>>>(
      y_h, w_out_h, out_part, nullptr, nullptr, DM, MR, DM, DI, DI / 4);
  out_reduce<<<(MR * DM / 4) / 256, 256, 0, stream>>>(x, out_part, out);
}

// Round 13
// 223.119 us; speedup vs baseline: 1.1321x; 1.0194x over previous
//
#include <hip/hip_runtime.h>
#include <hip/hip_bf16.h>
#include <math.h>

// Problem constants (from reference)
#define DM   1024        // d_model
#define DI   2048        // d_inner
#define DS   16          // d_state
#define DTR  64          // dt_rank
#define NB   2           // batch
#define LL   1024        // seq len
#define MR   (NB*LL)     // 2048 rows (b*l flattened)
#define XDBL 96          // dt_rank + 2*d_state
#define NC   32          // scan chunks
#define CL   32          // chunk length (NC*CL == LL)

typedef _Float16 half8  __attribute__((ext_vector_type(8)));
typedef _Float16 half4v __attribute__((ext_vector_type(4)));
typedef float    floatx4 __attribute__((ext_vector_type(4)));

__device__ __forceinline__ void gload_lds16(const void* g, void* l) {
  __builtin_amdgcn_global_load_lds(
      (const __attribute__((address_space(1))) void*)g,
      (__attribute__((address_space(3))) void*)l, 16, 0, 0);
}

// ---------------------------------------------------------------------------
// Front kernel: LN (blocks 0..2047) + weight f2h.
// ---------------------------------------------------------------------------
__global__ __launch_bounds__(256) void front_kernel(
    const float* __restrict__ x, const float* __restrict__ ln_w,
    const float* __restrict__ ln_b,
    const float* __restrict__ w_in, const float* __restrict__ w_out,
    const float* __restrict__ w_xp, const float* __restrict__ w_dt,
    _Float16* __restrict__ h_h,
    _Float16* __restrict__ w_in_h, _Float16* __restrict__ w_out_h,
    _Float16* __restrict__ w_xp_h, _Float16* __restrict__ w_dt_h) {
  const int blk = blockIdx.x;
  if (blk < MR) {
    __shared__ float sA[4], sB[4];
    const float* xr = x + (size_t)blk * DM;
    float s = 0.f, ss = 0.f;
    for (int i = threadIdx.x; i < DM; i += 256) {
      float v = xr[i];
      s += v; ss += v * v;
    }
    for (int o = 32; o > 0; o >>= 1) {
      s  += __shfl_down(s, o, 64);
      ss += __shfl_down(ss, o, 64);
    }
    const int wid = threadIdx.x >> 6, lid = threadIdx.x & 63;
    if (lid == 0) { sA[wid] = s; sB[wid] = ss; }
    __syncthreads();
    if (threadIdx.x == 0) {
      float S = sA[0] + sA[1] + sA[2] + sA[3];
      float SS = sB[0] + sB[1] + sB[2] + sB[3];
      float mu = S / DM;
      sA[0] = mu;
      sB[0] = rsqrtf(SS / DM - mu * mu + 1e-5f);
    }
    __syncthreads();
    const float mu = sA[0], rs = sB[0];
    for (int i = threadIdx.x; i < DM; i += 256)
      h_h[(size_t)blk * DM + i] = (_Float16)((xr[i] - mu) * rs * ln_w[i] + ln_b[i]);
    return;
  }
  int i = (blk - MR) * 256 + threadIdx.x;
  const int N0 = 1048576, N1 = 524288, N2 = 49152, N3 = 32768;
  const float* s; _Float16* d; int off;
  if (i < N0)            { s = w_in;  d = w_in_h;  off = i; }
  else if (i < N0+N1)    { s = w_out; d = w_out_h; off = i - N0; }
  else if (i < N0+N1+N2) { s = w_xp;  d = w_xp_h;  off = i - N0 - N1; }
  else if (i < N0+N1+N2+N3) { s = w_dt; d = w_dt_h; off = i - N0 - N1 - N2; }
  else return;
  float4 v = ((const float4*)s)[off];
  half4v h = {(_Float16)v.x, (_Float16)v.y, (_Float16)v.z, (_Float16)v.w};
  ((half4v*)d)[off] = h;
}

// ---------------------------------------------------------------------------
// MFMA f16 GEMM, double-buffered LDS pipeline + XOR bank swizzle.
// C[m,n] = sum_k A[m,k]*W[n,k], fp32 accumulate. Tile 128 x TN,
// slab = KS*32 k-cols per barrier (KS sub-steps, each BK=32 with the
// r10-proven zero-conflict layout). 4 waves each 64 x TN/2.
// r10/r11/r12 lessons: limiter = per-slab latency quantum (~500-900 cyc),
// NOT bank conflicts; fewer+fatter slabs win. KS=2 halves slab count.
// r7 lesson: f16 epilogue stores fine; use __logf/__expf (libm = SGPR-112
// slow path, 70us).
// EPI 0: dual f16 store (n<DI -> Cv, else C2v; compact DI-wide rows)
// EPI 4: f16 partial store at Cv + blockIdx.z*M*ldc (split-K, no atomics)
// EPI 5: f16 store softplus(acc + extra[n])  [fast-math]
// ---------------------------------------------------------------------------
template <int EPI, int TN, int KS>
__global__ __launch_bounds__(256) void gemm_mfma(
    const _Float16* __restrict__ A,   // [M][K]
    const _Float16* __restrict__ W,   // [N][K]
    void* __restrict__ Cv, void* __restrict__ C2v,
    const float* __restrict__ extra, int ldc,
    int M, int N, int K, int kchunk) {
  constexpr int NT = (TN + 31) / 32;   // 16-col tiles per wave
  constexpr int WSLOT = TN / 16;       // W staging slots per sub-slab
  constexpr int SLAB = 32 * KS;
  __shared__ alignas(16) _Float16 As[2][128 * 32 * KS];
  __shared__ alignas(16) _Float16 Ws[2][TN * 32 * KS];
  const int t = threadIdx.x;
  const int wave = t >> 6, lane = t & 63;
  const int m0 = blockIdx.y * 128, n0 = blockIdx.x * TN;
  const int k_beg = blockIdx.z * kchunk;
  const int nk = kchunk / SLAB;
  const int wm = (wave >> 1) * 64, wn = (wave & 1) * (TN / 2);
  floatx4 acc[4][NT];
#pragma unroll
  for (int i = 0; i < 4; i++)
#pragma unroll
    for (int j = 0; j < NT; j++) acc[i][j] = {0.f, 0.f, 0.f, 0.f};

  const int fr = lane & 15;     // row within 16-tile
  const int kc8 = lane >> 4;    // logical 8-half k-chunk this lane consumes
  const int kp = (kc8 ^ ((fr >> 1) & 3)) * 8;   // swizzled physical chunk

  auto stage = [&](int buf, int k0) {
    for (int sl = wave; sl < 8 * KS; sl += 4) {
      const int ss = sl >> 3, s8 = sl & 7;      // sub-slab, slot within
      const int idx = s8 * 64 + lane;
      const int row = idx >> 2;
      const int kc = (idx & 3) ^ ((row >> 1) & 3);   // XOR-swizzled fetch
      gload_lds16(A + (size_t)(m0 + row) * K + k0 + ss * 32 + kc * 8,
                  &As[buf][ss * 4096 + s8 * 512]);
    }
    for (int sl = wave; sl < WSLOT * KS; sl += 4) {
      const int ss = sl / WSLOT, sw = sl % WSLOT;
      const int idx = sw * 64 + lane;
      const int row = idx >> 2;
      const int kc = (idx & 3) ^ ((row >> 1) & 3);
      const int wrow = (n0 + row < N) ? row : 0;   // safety clamp
      gload_lds16(W + (size_t)(n0 + wrow) * K + k0 + ss * 32 + kc * 8,
                  &Ws[buf][ss * (TN * 32) + sw * 512]);
    }
  };

  stage(0, k_beg);
  int cur = 0;
  for (int ki = 0; ki < nk; ki++) {
    __syncthreads();                       // stage(cur) complete; prior reads done
    if (ki + 1 < nk) stage(cur ^ 1, k_beg + (ki + 1) * SLAB);   // async prefetch
#pragma unroll
    for (int ks = 0; ks < KS; ks++) {
      half8 af[4], wf[NT];
#pragma unroll
      for (int i = 0; i < 4; i++)
        af[i] = *(const half8*)&As[cur][ks * 4096 + (wm + i * 16 + fr) * 32 + kp];
#pragma unroll
      for (int j = 0; j < NT; j++)
        wf[j] = *(const half8*)&Ws[cur][ks * (TN * 32) + (wn + j * 16 + fr) * 32 + kp];
#pragma unroll
      for (int i = 0; i < 4; i++)
#pragma unroll
        for (int j = 0; j < NT; j++)
          acc[i][j] = __builtin_amdgcn_mfma_f32_16x16x32_f16(af[i], wf[j], acc[i][j], 0, 0, 0);
    }
    cur ^= 1;
  }

  // epilogue: C/D layout col = lane&15, row = (lane>>4)*4 + reg
  const int col = lane & 15, rowq = lane >> 4;
#pragma unroll
  for (int i = 0; i < 4; i++) {
#pragma unroll
    for (int j = 0; j < NT; j++) {
      const int n = n0 + wn + j * 16 + col;
      if (n < N) {
#pragma unroll
        for (int r = 0; r < 4; r++) {
          const int m = m0 + wm + i * 16 + rowq * 4 + r;
          float v = acc[i][j][r];
          if (EPI == 0) {
            if (n < DI) ((_Float16*)Cv )[(size_t)m * DI + n]      = (_Float16)v;
            else        ((_Float16*)C2v)[(size_t)m * DI + n - DI] = (_Float16)v;
          } else if (EPI == 4) {
            ((_Float16*)Cv)[((size_t)blockIdx.z * M + m) * ldc + n] = (_Float16)v;
          } else if (EPI == 5) {
            v += extra[n];
            v = (v > 20.f) ? v : __logf(1.f + __expf(v));   // fast softplus
            ((_Float16*)Cv)[(size_t)m * ldc + n] = (_Float16)v;
          }
        }
      }
    }
  }
}

// ---------------------------------------------------------------------------
// x_proj partial reduce (f16 partials): x_dbl = sum_z part[z], emit dtr f16.
// ---------------------------------------------------------------------------
__global__ __launch_bounds__(256) void xproj_reduce(
    const _Float16* __restrict__ part,   // [16][MR][XDBL] f16
    float* __restrict__ x_dbl, _Float16* __restrict__ dtr) {
  const int idx = blockIdx.x * 256 + threadIdx.x;   // MR*XDBL = 196608
  const int m = idx / XDBL, c = idx - m * XDBL;
  float s = 0.f;
#pragma unroll
  for (int z = 0; z < 16; z++) s += (float)part[(size_t)z * (MR * XDBL) + idx];
  x_dbl[idx] = s;
  if (c < DTR) dtr[m * DTR + c] = (_Float16)s;
}

// ---------------------------------------------------------------------------
// out_proj partial reduce + residual: out = x + sum of 4 f16 partials.
// ---------------------------------------------------------------------------
__global__ __launch_bounds__(256) void out_reduce(
    const float* __restrict__ x, const _Float16* __restrict__ part,  // [4][MR][DM]
    float* __restrict__ out) {
  const int i = blockIdx.x * 256 + threadIdx.x;   // MR*DM/4 = 524288
  float4 a = ((const float4*)x)[i];
#pragma unroll
  for (int z = 0; z < 4; z++) {
    half4v p = ((const half4v*)(part + (size_t)z * MR * DM))[i];
    a.x += (float)p.x; a.y += (float)p.y; a.z += (float)p.z; a.w += (float)p.w;
  }
  ((float4*)out)[i] = a;
}

// ---------------------------------------------------------------------------
// Depthwise causal conv1d (width 4) + bias + SiLU, 8 channels per thread.
// ---------------------------------------------------------------------------
__global__ __launch_bounds__(256) void conv_silu_kernel(
    const _Float16* __restrict__ xin, const float* __restrict__ cw,
    const float* __restrict__ cb, _Float16* __restrict__ xc) {
  const int idx = blockIdx.x * 256 + threadIdx.x;   // 0 .. MR*DI/8-1
  const int d8 = idx & (DI / 8 - 1);
  const int ml = idx >> 8;
  const int l  = ml & (LL - 1);
  const int d0 = d8 * 8;
  half8 xr[4];
  const half8 zero = {0, 0, 0, 0, 0, 0, 0, 0};
#pragma unroll
  for (int k = 0; k < 4; k++) {
    const int lp = l - 3 + k;
    xr[k] = (lp >= 0) ? *(const half8*)&xin[(size_t)(ml - 3 + k) * DI + d0] : zero;
  }
  half8 o;
#pragma unroll
  for (int j = 0; j < 8; j++) {
    float acc = cb[d0 + j];
#pragma unroll
    for (int k = 0; k < 4; k++)
      acc += (float)xr[k][j] * cw[(d0 + j) * 4 + k];
    o[j] = (_Float16)(acc / (1.f + __expf(-acc)));
  }
  *(half8*)&xc[(size_t)ml * DI + d0] = o;
}

// ---------------------------------------------------------------------------
// Load per-channel A row; detect S4D-real init a[s] == -(s+1) (uniform).
// ---------------------------------------------------------------------------
__device__ __forceinline__ bool load_a(const float* __restrict__ A_log, int d,
                                       float* a) {
  const float4* Ap = (const float4*)(A_log + (size_t)d * DS);
  bool fast = true;
#pragma unroll
  for (int i = 0; i < 4; i++) {
    float4 v = Ap[i];
    a[4 * i + 0] = -__expf(v.x); a[4 * i + 1] = -__expf(v.y);
    a[4 * i + 2] = -__expf(v.z); a[4 * i + 3] = -__expf(v.w);
  }
#pragma unroll
  for (int s = 0; s < DS; s++)
    fast = fast && (fabsf(a[s] + (float)(s + 1)) < 1e-4f);
  return fast;
}

// ---------------------------------------------------------------------------
// Chunked selective scan, phase 1: per-(b,chunk) local scan with h=0 init.
// Fast path: exp(dt*a[s]) = r^(s+1), r = exp(-dt)  (1 exp + 15 mul vs 16 exp).
// ---------------------------------------------------------------------------
__global__ __launch_bounds__(256) void scan_phase1(
    const _Float16* __restrict__ xc,  // x_conv (MR x DI) f16
    const float* __restrict__ xdbl,   // (MR x 96)
    const _Float16* __restrict__ dtm, // dt after softplus (MR x DI) f16
    const float* __restrict__ A_log,
    float* __restrict__ HE,           // (NB*NC*DS) x DI
    float* __restrict__ SA) {         // (NB*NC) x DI
  __shared__ float Bs[CL][DS];
  const int bi = blockIdx.x;
  const int dblk = bi & 7;
  const int c = (bi >> 3) & (NC - 1);
  const int b = bi >> 8;
  const int t = threadIdx.x;
  const int d = dblk * 256 + t;
  const int mlbase = b * LL + c * CL;

  for (int i = t; i < CL * DS; i += 256) {
    int tt = i >> 4, s = i & 15;
    Bs[tt][s] = xdbl[(size_t)(mlbase + tt) * XDBL + DTR + s];
  }

  float a[DS];
  const bool fast = load_a(A_log, d, a);
  float h[DS];
#pragma unroll
  for (int s = 0; s < DS; s++) h[s] = 0.f;
  float S = 0.f;
  __syncthreads();

  if (fast) {
    for (int tt = 0; tt < CL; tt++) {
      const size_t ml = mlbase + tt;
      const float dtv = (float)dtm[ml * DI + d];
      const float u   = (float)xc[ml * DI + d];
      const float du  = dtv * u;
      S += dtv;
      const float r = __expf(-dtv);
      float P = 1.f;
#pragma unroll
      for (int s = 0; s < DS; s++) {
        P *= r;
        h[s] = P * h[s] + du * Bs[tt][s];
      }
    }
  } else {
    for (int tt = 0; tt < CL; tt++) {
      const size_t ml = mlbase + tt;
      const float dtv = (float)dtm[ml * DI + d];
      const float u   = (float)xc[ml * DI + d];
      const float du  = dtv * u;
      S += dtv;
#pragma unroll
      for (int s = 0; s < DS; s++)
        h[s] = __expf(dtv * a[s]) * h[s] + du * Bs[tt][s];
    }
  }
  const size_t base = ((size_t)(b * NC + c) * DS) * DI + d;
#pragma unroll
  for (int s = 0; s < DS; s++) HE[base + (size_t)s * DI] = h[s];
  SA[(size_t)(b * NC + c) * DI + d] = S;
}

// ---------------------------------------------------------------------------
// Phase 2: sequential combine over chunk aggregates; HE becomes carry-in.
// ---------------------------------------------------------------------------
__global__ __launch_bounds__(256) void scan_phase2(
    const float* __restrict__ A_log,
    const float* __restrict__ SA,
    float* __restrict__ HE) {
  const int idx = blockIdx.x * 256 + threadIdx.x;  // NB*DS*DI
  const int d = idx & (DI - 1);
  const int s = (idx >> 11) & (DS - 1);
  const int b = idx >> 15;
  const float a = -__expf(A_log[(size_t)d * DS + s]);
  float Hc = 0.f;
  for (int c = 0; c < NC; c++) {
    const size_t o = ((size_t)(b * NC + c) * DS + s) * DI + d;
    const float he = HE[o];
    const float P = __expf(a * SA[(size_t)(b * NC + c) * DI + d]);
    HE[o] = Hc;
    Hc = P * Hc + he;
  }
}

// ---------------------------------------------------------------------------
// Phase 3: re-run chunks with carry-in; fuse y = (sum_s h*C + u*D)*silu(z).
// ---------------------------------------------------------------------------
__global__ __launch_bounds__(256) void scan_phase3(
    const _Float16* __restrict__ xc,
    const float* __restrict__ xdbl,
    const _Float16* __restrict__ dtm,   // f16
    const _Float16* __restrict__ zbuf,  // z (MR x DI) f16
    const float* __restrict__ A_log,
    const float* __restrict__ Dvec,
    const float* __restrict__ HE,
    _Float16* __restrict__ y) {         // (MR x DI) f16
  __shared__ float Bs[CL][DS];
  __shared__ float Cs[CL][DS];
  const int bi = blockIdx.x;
  const int dblk = bi & 7;
  const int c = (bi >> 3) & (NC - 1);
  const int b = bi >> 8;
  const int t = threadIdx.x;
  const int d = dblk * 256 + t;
  const int mlbase = b * LL + c * CL;

  for (int i = t; i < CL * DS; i += 256) {
    int tt = i >> 4, s = i & 15;
    const size_t ro = (size_t)(mlbase + tt) * XDBL + DTR + s;
    Bs[tt][s] = xdbl[ro];
    Cs[tt][s] = xdbl[ro + DS];
  }

  float a[DS];
  const bool fast = load_a(A_log, d, a);
  float h[DS];
  const size_t base = ((size_t)(b * NC + c) * DS) * DI + d;
#pragma unroll
  for (int s = 0; s < DS; s++) h[s] = HE[base + (size_t)s * DI];
  const float Dv = Dvec[d];
  __syncthreads();

  if (fast) {
    for (int tt = 0; tt < CL; tt++) {
      const size_t ml = mlbase + tt;
      const float dtv = (float)dtm[ml * DI + d];
      const float u   = (float)xc[ml * DI + d];
      const float du  = dtv * u;
      const float r = __expf(-dtv);
      float P = 1.f, p = 0.f;
#pragma unroll
      for (int s = 0; s < DS; s++) {
        P *= r;
        h[s] = P * h[s] + du * Bs[tt][s];
        p += h[s] * Cs[tt][s];
      }
      const float zv = (float)zbuf[ml * DI + d];
      const float sil = zv / (1.f + __expf(-zv));
      y[ml * DI + d] = (_Float16)((p + u * Dv) * sil);
    }
  } else {
    for (int tt = 0; tt < CL; tt++) {
      const size_t ml = mlbase + tt;
      const float dtv = (float)dtm[ml * DI + d];
      const float u   = (float)xc[ml * DI + d];
      const float du  = dtv * u;
      float p = 0.f;
#pragma unroll
      for (int s = 0; s < DS; s++) {
        h[s] = __expf(dtv * a[s]) * h[s] + du * Bs[tt][s];
        p += h[s] * Cs[tt][s];
      }
      const float zv = (float)zbuf[ml * DI + d];
      const float sil = zv / (1.f + __expf(-zv));
      y[ml * DI + d] = (_Float16)((p + u * Dv) * sil);
    }
  }
}

// ---------------------------------------------------------------------------
// Launch
// ---------------------------------------------------------------------------
extern "C" void kernel_launch(void* const* d_in, const int* in_sizes, int n_in,
                              void* d_out, int out_size, void* d_ws, size_t ws_size,
                              hipStream_t stream) {
  const float* x         = (const float*)d_in[0];
  const float* ln_w      = (const float*)d_in[1];
  const float* ln_b      = (const float*)d_in[2];
  const float* in_proj_w = (const float*)d_in[3];   // (4096, 1024)
  const float* conv_w    = (const float*)d_in[4];   // (2048, 1, 4)
  const float* conv_b    = (const float*)d_in[5];
  const float* x_proj_w  = (const float*)d_in[6];   // (96, 2048)
  const float* dt_proj_w = (const float*)d_in[7];   // (2048, 64)
  const float* dt_proj_b = (const float*)d_in[8];
  const float* A_log     = (const float*)d_in[9];   // (2048, 16)
  const float* Dvec      = (const float*)d_in[10];
  const float* out_proj_w= (const float*)d_in[11];  // (1024, 2048)
  float* out = (float*)d_out;

  // workspace layout (bytes; total ~75.6 MB)
  char* ws = (char*)d_ws;
  _Float16* h_h      = (_Float16*)ws;                 //  4 MB — dead after in_proj
  _Float16* xin_h    = (_Float16*)(ws + 4194304);     //  8 MB — dead after conv
  _Float16* y_h      = xin_h;                         //  aliases xin
  _Float16* z_h      = (_Float16*)(ws + 12582912);    //  8 MB
  _Float16* xc_h     = (_Float16*)(ws + 20971520);    //  8 MB
  _Float16* dtb_h    = (_Float16*)(ws + 29360128);    //  8 MB f16 — dead after p3
  _Float16* out_part = dtb_h;                         // 16 MB (4 x MR*DM f16)
  float*    x_dbl    = (float*)   (ws + 46137344);    //  0.75 MB
  float*    SA       = (float*)   (ws + 46923776);    //  0.5 MB
  _Float16* dtr_h    = (_Float16*)(ws + 47448064);    //  0.25 MB
  float*    HE       = (float*)   (ws + 47710208);    //  8 MB
  _Float16* w_in_h   = (_Float16*)(ws + 56098816);    //  8 MB
  _Float16* w_out_h  = (_Float16*)(ws + 64487424);    //  4 MB
  _Float16* w_xp_h   = (_Float16*)(ws + 68681728);    //  0.375 MB
  _Float16* w_dt_h   = (_Float16*)(ws + 69074944);    //  0.25 MB
  _Float16* xp_part  = (_Float16*)(ws + 69337088);    //  6 MB (16 x MR x 96 f16)

  // 0+1. fused: layernorm + weight f2h
  front_kernel<<<MR + 6464, 256, 0, stream>>>(
      x, ln_w, ln_b, in_proj_w, out_proj_w, x_proj_w, dt_proj_w,
      h_h, w_in_h, w_out_h, w_xp_h, w_dt_h);

  // 2. in_proj: N=4096, tile 128x128, 64-wide slabs -> 16 slabs, 512 blocks
  gemm_mfma<0, 128, 2><<<dim3(2 * DI / 128, MR / 128, 1), 256, 0, stream>>>(
      h_h, w_in_h, xin_h, z_h, nullptr, 0, MR, 2 * DI, DM, DM);

  // 3. conv + silu -> xc_h (f16), 8 channels/thread
  conv_silu_kernel<<<(MR * DI / 8) / 256, 256, 0, stream>>>(xin_h, conv_w, conv_b, xc_h);

  // 4. x_proj: tile 128x96, split-K 16, 2 slabs each -> f16 partials
  gemm_mfma<4, 96, 2><<<dim3(1, MR / 128, 16), 256, 0, stream>>>(
      xc_h, w_xp_h, xp_part, nullptr, nullptr, XDBL, MR, XDBL, DI, DI / 16);
  xproj_reduce<<<(MR * XDBL) / 256, 256, 0, stream>>>(xp_part, x_dbl, dtr_h);

  // 5. dt: K=64 = single slab (one barrier) + fast softplus -> f16 dtb
  gemm_mfma<5, 64, 2><<<dim3(DI / 64, MR / 128, 1), 256, 0, stream>>>(
      dtr_h, w_dt_h, dtb_h, nullptr, dt_proj_b, DI, MR, DI, DTR, DTR);

  // 6. chunked selective scan
  scan_phase1<<<NB * NC * (DI / 256), 256, 0, stream>>>(
      xc_h, x_dbl, dtb_h, A_log, HE, SA);
  scan_phase2<<<(NB * DS * DI) / 256, 256, 0, stream>>>(A_log, SA, HE);
  scan_phase3<<<NB * NC * (DI / 256), 256, 0, stream>>>(
      xc_h, x_dbl, dtb_h, z_h, A_log, Dvec, HE, y_h);

  // 7. out_proj: tile 128x128, split-K 4, 8 slabs -> f16 partials, then
  //    out = x + sum(partials)
  gemm_mfma<4, 128, 2><<<dim3(DM / 128, MR / 128, 4), 256, 0, stream>>>(
      y_h, w_out_h, out_part, nullptr, nullptr, DM, MR, DM, DI, DI / 4);
  out_reduce<<<(MR * DM / 4) / 256, 256, 0, stream>>>(x, out_part, out);
}